// Round 1
// baseline (848.064 us; speedup 1.0000x reference)
//
#include <hip/hip_runtime.h>

#define NR 64          // NX == NY
#define NH 256         // H
#define NP1 65
#define CSTRIDE 68     // padded row stride for C/E (16B-aligned, conflict-friendly)
#define TSTRIDE 68     // padded row stride for transposed staging tiles
#define NITER 20

__device__ __forceinline__ float dot4(float4 a, float4 b) {
  return a.x * b.x + a.y * b.y + a.z * b.z + a.w * b.w;
}

__global__ __launch_bounds__(256, 2)
void sinkhorn_kernel(const float* __restrict__ x, const float* __restrict__ y,
                     const float* __restrict__ gam, const float* __restrict__ bet,
                     const float* __restrict__ wdb, const float* __restrict__ bdb,
                     float* __restrict__ out_match, float* __restrict__ out_score)
{
  const int b = blockIdx.x;
  const int t = threadIdx.x;
  const int lane = t & 63;

  // phase1: xsT[64][68] | ysT[64][68];  phase2 (aliased): Cm[65][68] | Em[65][68]
  __shared__ __align__(16) float s_buf[2 * NP1 * CSTRIDE];   // 8840 floats = 35.4 KB
  __shared__ __align__(16) float s_gw[NH];
  __shared__ float s_sx[NR], s_ax[NR], s_sy[NR], s_ay[NR];
  __shared__ __align__(16) float s_u[NP1 + 3], s_v[NP1 + 3];
  __shared__ __align__(16) float s_eu[NP1 + 3], s_ev[NP1 + 3];
  __shared__ float s_red[8];
  __shared__ float s_S12[2];

  float* xsT = s_buf;                   // [k][i], k in chunk, stride TSTRIDE
  float* ysT = s_buf + NR * TSTRIDE;
  float* Cm  = s_buf;                   // [65][CSTRIDE]
  float* Em  = s_buf + NP1 * CSTRIDE;

  const float norm_c  = -4.852030263919617f;    // -log(128)
  const float logmu64 = -0.6931471805599453f;   // log(64) - log(128)

  // ---------------- phase 0: gw = gamma*w, S1 = sum(gw), S2 = sum(beta*w)+b
  {
    float gv = gam[t];
    float wv = wdb[t];
    float p1 = gv * wv;
    float p2 = bet[t] * wv;
    s_gw[t] = p1;
    #pragma unroll
    for (int o = 1; o < 64; o <<= 1) { p1 += __shfl_xor(p1, o); p2 += __shfl_xor(p2, o); }
    if (lane == 0) { s_red[(t >> 6) * 2] = p1; s_red[(t >> 6) * 2 + 1] = p2; }
  }
  __syncthreads();
  if (t == 0) {
    s_S12[0] = s_red[0] + s_red[2] + s_red[4] + s_red[6];
    s_S12[1] = s_red[1] + s_red[3] + s_red[5] + s_red[7] + bdb[0];
  }

  // ---------------- phase 1: staged (transposed) load + row stats + 64x64x256 matmul
  const int ti = t >> 4;       // 0..15
  const int tj = t & 15;       // 0..15
  const int i0 = ti * 4, j0 = tj * 4;
  const int lh4 = tj * 4;      // float offset within 64-float chunk of a row

  float acc[4][4] = {};
  float xsum[4] = {}, xsq[4] = {}, xdg[4] = {};
  float ysum[4] = {}, ysq[4] = {}, ydg[4] = {};

  const size_t gbase = (size_t)b * NR * NH;

  for (int ch = 0; ch < 4; ++ch) {
    __syncthreads();   // previous chunk's matmul reads done before overwrite
    const float4 gw4 = *(const float4*)(s_gw + ch * 64 + lh4);
    #pragma unroll
    for (int j = 0; j < 4; ++j) {
      const int row = ti + 16 * j;
      const float4 xv = *(const float4*)(x + gbase + (size_t)row * NH + ch * 64 + lh4);
      xsum[j] += xv.x + xv.y + xv.z + xv.w;
      xsq[j]  += dot4(xv, xv);
      xdg[j]  += dot4(xv, gw4);
      xsT[(lh4 + 0) * TSTRIDE + row] = xv.x;
      xsT[(lh4 + 1) * TSTRIDE + row] = xv.y;
      xsT[(lh4 + 2) * TSTRIDE + row] = xv.z;
      xsT[(lh4 + 3) * TSTRIDE + row] = xv.w;
      const float4 yv = *(const float4*)(y + gbase + (size_t)row * NH + ch * 64 + lh4);
      ysum[j] += yv.x + yv.y + yv.z + yv.w;
      ysq[j]  += dot4(yv, yv);
      ydg[j]  += dot4(yv, gw4);
      ysT[(lh4 + 0) * TSTRIDE + row] = yv.x;
      ysT[(lh4 + 1) * TSTRIDE + row] = yv.y;
      ysT[(lh4 + 2) * TSTRIDE + row] = yv.z;
      ysT[(lh4 + 3) * TSTRIDE + row] = yv.w;
    }
    __syncthreads();
    #pragma unroll 4
    for (int k = 0; k < 64; ++k) {
      const float4 a4 = *(const float4*)(xsT + k * TSTRIDE + i0);
      const float4 b4 = *(const float4*)(ysT + k * TSTRIDE + j0);
      acc[0][0] += a4.x * b4.x; acc[0][1] += a4.x * b4.y; acc[0][2] += a4.x * b4.z; acc[0][3] += a4.x * b4.w;
      acc[1][0] += a4.y * b4.x; acc[1][1] += a4.y * b4.y; acc[1][2] += a4.y * b4.z; acc[1][3] += a4.y * b4.w;
      acc[2][0] += a4.z * b4.x; acc[2][1] += a4.z * b4.y; acc[2][2] += a4.z * b4.z; acc[2][3] += a4.z * b4.w;
      acc[3][0] += a4.w * b4.x; acc[3][1] += a4.w * b4.y; acc[3][2] += a4.w * b4.z; acc[3][3] += a4.w * b4.w;
    }
  }

  // reduce stats across the 16 lanes sharing the same row set
  #pragma unroll
  for (int o = 1; o < 16; o <<= 1) {
    #pragma unroll
    for (int j = 0; j < 4; ++j) {
      xsum[j] += __shfl_xor(xsum[j], o);
      xsq[j]  += __shfl_xor(xsq[j], o);
      xdg[j]  += __shfl_xor(xdg[j], o);
      ysum[j] += __shfl_xor(ysum[j], o);
      ysq[j]  += __shfl_xor(ysq[j], o);
      ydg[j]  += __shfl_xor(ydg[j], o);
    }
  }
  {
    const float S1 = s_S12[0], S2 = s_S12[1];
    if (tj == 0) {
      #pragma unroll
      for (int j = 0; j < 4; ++j) {
        const int r = ti + 16 * j;
        float mu   = xsum[j] * (1.0f / NH);
        float var  = xsq[j] * (1.0f / NH) - mu * mu;
        float rstd = rsqrtf(var + 1e-5f);
        s_ax[r] = tanhf(rstd * (xdg[j] - mu * S1) + S2);
        s_sx[r] = 1.0f / fmaxf(sqrtf(xsq[j]), 1e-12f);
        mu   = ysum[j] * (1.0f / NH);
        var  = ysq[j] * (1.0f / NH) - mu * mu;
        rstd = rsqrtf(var + 1e-5f);
        s_ay[r] = tanhf(rstd * (ydg[j] - mu * S1) + S2);
        s_sy[r] = 1.0f / fmaxf(sqrtf(ysq[j]), 1e-12f);
      }
    }
  }
  __syncthreads();   // stats ready; all matmul LDS reads complete -> safe to alias C/E

  // ---------------- build C = couplings/reg and E = exp(C) in LDS
  {
    float sxr[4], syc[4];
    #pragma unroll
    for (int r = 0; r < 4; ++r) sxr[r] = s_sx[i0 + r];
    #pragma unroll
    for (int c = 0; c < 4; ++c) syc[c] = s_sy[j0 + c];
    #pragma unroll
    for (int r = 0; r < 4; ++r) {
      #pragma unroll
      for (int c = 0; c < 4; ++c) {
        const float Cij = acc[r][c] * sxr[r] * syc[c] * 10.0f;   // /REG
        Cm[(i0 + r) * CSTRIDE + (j0 + c)] = Cij;
        Em[(i0 + r) * CSTRIDE + (j0 + c)] = __expf(Cij);
      }
    }
  }
  if (t < NR) {
    const float cx = 10.0f * s_ax[t];
    Cm[t * CSTRIDE + 64] = cx;
    Em[t * CSTRIDE + 64] = __expf(cx);
    const float cy = 10.0f * s_ay[t];
    Cm[64 * CSTRIDE + t] = cy;
    Em[64 * CSTRIDE + t] = __expf(cy);
  }
  if (t == 64) {
    Cm[64 * CSTRIDE + 64] = -1000.0f;
    Em[64 * CSTRIDE + 64] = 0.0f;       // exp(-1000) underflows to 0, same as ref
  }
  if (t < NP1 + 3) { s_ev[t] = 1.0f; s_v[t] = 0.0f; s_u[t] = 0.0f; s_eu[t] = 1.0f; }
  __syncthreads();

  // ---------------- Sinkhorn: 20 iterations in the exp domain
  const int rr = t >> 2;   // row (u-pass) / col (v-pass), 0..63
  const int cc = t & 3;    // quarter
  const float* Erow   = Em + rr * CSTRIDE + 16 * cc;
  const float* Erow64 = Em + 64 * CSTRIDE + 16 * t;   // valid only for t<4

  for (int it = 0; it < NITER; ++it) {
    // ---- u update: u_i = log_mu_i - log(sum_j E[i][j]*ev[j])
    float s = 0.0f;
    #pragma unroll
    for (int q = 0; q < 4; ++q) {
      const float4 e4 = *(const float4*)(Erow + 4 * q);
      const float4 v4 = *(const float4*)(s_ev + 16 * cc + 4 * q);
      s += dot4(e4, v4);
    }
    if (cc == 0) s += Em[rr * CSTRIDE + 64] * s_ev[64];
    float s2 = 0.0f;
    if (t < 4) {   // dustbin row 64 handled by lanes 0..3 of wave 0
      #pragma unroll
      for (int q = 0; q < 4; ++q) {
        const float4 e4 = *(const float4*)(Erow64 + 4 * q);
        const float4 v4 = *(const float4*)(s_ev + 16 * t + 4 * q);
        s2 += dot4(e4, v4);
      }
      // corner E==0 contributes nothing
    }
    s += __shfl_xor(s, 1);
    s += __shfl_xor(s, 2);
    if (cc == 0) {
      const float u_ = norm_c - __logf(s);
      s_u[rr] = u_;
      s_eu[rr] = __expf(u_);
    }
    if (t < 4) {
      s2 += __shfl_xor(s2, 1);
      s2 += __shfl_xor(s2, 2);
      if (t == 0) {
        const float u_ = logmu64 - __logf(s2);
        s_u[64] = u_;
        s_eu[64] = __expf(u_);
      }
    }
    __syncthreads();

    // ---- v update: v_j = log_nu_j - log(sum_i E[i][j]*eu[i])
    float euv[16];
    #pragma unroll
    for (int q = 0; q < 4; ++q) {
      const float4 e = *(const float4*)(s_eu + 16 * cc + 4 * q);
      euv[4 * q + 0] = e.x; euv[4 * q + 1] = e.y; euv[4 * q + 2] = e.z; euv[4 * q + 3] = e.w;
    }
    float sv = 0.0f;
    #pragma unroll
    for (int m = 0; m < 16; ++m) {
      sv += Em[(16 * cc + m) * CSTRIDE + rr] * euv[m];
    }
    if (cc == 0) sv += Em[64 * CSTRIDE + rr] * s_eu[64];
    float sv2 = 0.0f;
    if (t < 4) {   // dustbin col 64; note euv already holds s_eu[16t..16t+15]
      #pragma unroll
      for (int m = 0; m < 16; ++m) {
        sv2 += Em[(16 * t + m) * CSTRIDE + 64] * euv[m];
      }
    }
    sv += __shfl_xor(sv, 1);
    sv += __shfl_xor(sv, 2);
    if (cc == 0) {
      const float v_ = norm_c - __logf(sv);
      s_v[rr] = v_;
      s_ev[rr] = __expf(v_);
    }
    if (t < 4) {
      sv2 += __shfl_xor(sv2, 1);
      sv2 += __shfl_xor(sv2, 2);
      if (t == 0) {
        const float v_ = logmu64 - __logf(sv2);
        s_v[64] = v_;
        s_ev[64] = __expf(v_);
      }
    }
    __syncthreads();
  }

  // ---------------- outputs: matching (b,65,65) and fused score
  float sacc = 0.0f;
  const size_t mbase = (size_t)b * (NP1 * NP1);
  for (int f = t; f < NP1 * NP1; f += 256) {
    const int row = f / 65;
    const int col = f - row * 65;
    const float Cij = Cm[row * CSTRIDE + col];
    const float mm = Cij + s_u[row] + s_v[col] - norm_c;
    out_match[mbase + f] = mm;
    if (row < 64 && col < 64) sacc += __expf(mm) * Cij;  // scores/temp == C (reg==temp)
  }
  #pragma unroll
  for (int o = 1; o < 64; o <<= 1) sacc += __shfl_xor(sacc, o);
  __syncthreads();
  if (lane == 0) s_red[t >> 6] = sacc;
  __syncthreads();
  if (t == 0) out_score[b] = s_red[0] + s_red[1] + s_red[2] + s_red[3];
}

extern "C" void kernel_launch(void* const* d_in, const int* in_sizes, int n_in,
                              void* d_out, int out_size, void* d_ws, size_t ws_size,
                              hipStream_t stream) {
  const float* x   = (const float*)d_in[0];
  const float* y   = (const float*)d_in[1];
  const float* gam = (const float*)d_in[2];
  const float* bet = (const float*)d_in[3];
  const float* wdb = (const float*)d_in[4];
  const float* bdb = (const float*)d_in[5];
  float* out_match = (float*)d_out;
  float* out_score = (float*)d_out + (size_t)4096 * 4225;
  sinkhorn_kernel<<<4096, 256, 0, stream>>>(x, y, gam, bet, wdb, bdb, out_match, out_score);
}